// Round 8
// baseline (328.113 us; speedup 1.0000x reference)
//
#include <hip/hip_runtime.h>
#include <math.h>

// MoE gate: gate = inp[16384,2048]f32 @ W[64,2048]^T + b[64]; top-2; softmax.
// d_out (float32): [tokens*2] indices-as-floats, then [tokens*2] scores.
//
// Round 10: r7 gate + atomic-finisher fusion (reduce dispatch eliminated).
// Ledger: fills 156us fixed; gate stuck ~48us across 3 structural variants
// (2-barrier, dbuf, 4x8: all 214.5-215.1 total) -> gate micro-structure is
// not the lever; the separate reduce kernel (+launch gap, ~12-14us) is the
// last mechanically-removable cost. Last-arriving split block per token-tile
// (agent-scope atomicAdd on a zeroed d_ws counter; no spinning -> no
// co-residency assumption) runs the exact reduce_topk body for its 128
// tokens, reading all S partials from global exactly as the old kernel did:
// bit-identical arithmetic, order, and tie-breaks -> absmax stays 0.0.
// Cross-XCD: release threadfence + acq_rel agent atomic + acquire agent
// fence (Guideline-16 pattern). Counters zeroed via 512B hipMemsetAsync.

#define KDIM 2048
#define NEXP 64
#define TM 128
#define BK 32
#define LDSA 132  // 128 tokens + 4 pad: 528 B stride (mult of 16 -> b128 ok)
#define LDSW 68   // 64 experts + 4 pad: 272 B stride

__global__ __launch_bounds__(256) void gate_fused_kernel(
    const float* __restrict__ inp,
    const float* __restrict__ W,
    const float* __restrict__ bias,
    float* __restrict__ partial,   // [S][tokens][NEXP]
    int* __restrict__ ctr,         // [tokens/TM], zeroed by memset
    float* __restrict__ out,
    int tokens, int kPerSplit, int S)
{
    __shared__ float As[2][BK][LDSA];   // As[buf][k][token]  (33.8 KB)
    __shared__ float Ws[2][BK][LDSW];   // Ws[buf][k][expert] (17.4 KB)
    __shared__ int lastFlag;

    const int tid = threadIdx.x;
    const int tx  = tid & 7;         // experts 8*tx..8*tx+7
    const int ty  = tid >> 3;        // tokens 4*ty..4*ty+3 (0..31)
    const int tokBase = blockIdx.x * TM;
    const int split   = blockIdx.y;
    const int k0      = split * kPerSplit;

    // A staging: 128 rows x 32 k; 2 threads/row, 16 k each (4 float4)
    const int arow = tid >> 1;           // 0..127
    const int acol = (tid & 1) << 4;     // 0 or 16
    // W staging: 64 rows x 32 k; 4 threads/row, 8 k each (2 float4)
    const int wrow = tid >> 2;           // 0..63
    const int wcol = (tid & 3) << 3;     // 0,8,16,24

    const float* aPtr = inp + (size_t)(tokBase + arow) * KDIM + k0 + acol;
    const float* wPtr = W   + (size_t)wrow * KDIM + k0 + wcol;

    float4 aReg[4], wReg[2];
    #pragma unroll
    for (int q = 0; q < 4; ++q) aReg[q] = *(const float4*)(aPtr + 4 * q);
    #pragma unroll
    for (int q = 0; q < 2; ++q) wReg[q] = *(const float4*)(wPtr + 4 * q);

    const int NT = kPerSplit / BK;

    // stage tile 0 into buffer 0 (transpose to [k][token]/[k][expert])
    #pragma unroll
    for (int q = 0; q < 4; ++q)
        #pragma unroll
        for (int j = 0; j < 4; ++j)
            As[0][acol + 4 * q + j][arow] = ((const float*)&aReg[q])[j];
    #pragma unroll
    for (int q = 0; q < 2; ++q)
        #pragma unroll
        for (int j = 0; j < 4; ++j)
            Ws[0][wcol + 4 * q + j][wrow] = ((const float*)&wReg[q])[j];

    if (NT > 1) {
        #pragma unroll
        for (int q = 0; q < 4; ++q) aReg[q] = *(const float4*)(aPtr + BK + 4 * q);
        #pragma unroll
        for (int q = 0; q < 2; ++q) wReg[q] = *(const float4*)(wPtr + BK + 4 * q);
    }
    __syncthreads();

    float acc[4][8];
    #pragma unroll
    for (int r = 0; r < 4; ++r)
        #pragma unroll
        for (int c = 0; c < 8; ++c) acc[r][c] = 0.0f;

    for (int kt = 0; kt < NT; ++kt) {
        const int cur = kt & 1;
        const int nxt = cur ^ 1;

        #pragma unroll 8
        for (int kk = 0; kk < BK; ++kk) {
            const float4 av  = *(const float4*)&As[cur][kk][ty << 2];
            const float4 wv0 = *(const float4*)&Ws[cur][kk][tx << 3];
            const float4 wv1 = *(const float4*)&Ws[cur][kk][(tx << 3) + 4];
            const float a[4] = {av.x, av.y, av.z, av.w};
            const float w[8] = {wv0.x, wv0.y, wv0.z, wv0.w,
                                wv1.x, wv1.y, wv1.z, wv1.w};
            #pragma unroll
            for (int r = 0; r < 4; ++r)
                #pragma unroll
                for (int c = 0; c < 8; ++c)
                    acc[r][c] = fmaf(a[r], w[c], acc[r][c]);
        }

        if (kt + 1 < NT) {
            #pragma unroll
            for (int q = 0; q < 4; ++q)
                #pragma unroll
                for (int j = 0; j < 4; ++j)
                    As[nxt][acol + 4 * q + j][arow] = ((const float*)&aReg[q])[j];
            #pragma unroll
            for (int q = 0; q < 2; ++q)
                #pragma unroll
                for (int j = 0; j < 4; ++j)
                    Ws[nxt][wcol + 4 * q + j][wrow] = ((const float*)&wReg[q])[j];
            if (kt + 2 < NT) {
                const int off = (kt + 2) * BK;
                #pragma unroll
                for (int q = 0; q < 4; ++q)
                    aReg[q] = *(const float4*)(aPtr + off + 4 * q);
                #pragma unroll
                for (int q = 0; q < 2; ++q)
                    wReg[q] = *(const float4*)(wPtr + off + 4 * q);
            }
        }
        __syncthreads();
    }

    // write partials: [split][token][expert]; 2 float4 per token row
    const int eBase = tx << 3;
    #pragma unroll
    for (int r = 0; r < 4; ++r) {
        const int token = tokBase + (ty << 2) + r;
        float* p = &partial[((size_t)split * tokens + token) * NEXP + eBase];
        *(float4*)(p)     = make_float4(acc[r][0], acc[r][1], acc[r][2], acc[r][3]);
        *(float4*)(p + 4) = make_float4(acc[r][4], acc[r][5], acc[r][6], acc[r][7]);
    }

    // ---- atomic-finisher: last split block of this tile runs the reduce ----
    __threadfence();               // release: flush this thread's stores
    __syncthreads();               // all threads of block have fenced
    if (tid == 0) {
        const int old = __hip_atomic_fetch_add(&ctr[blockIdx.x], 1,
                            __ATOMIC_ACQ_REL, __HIP_MEMORY_SCOPE_AGENT);
        lastFlag = (old == S - 1);
    }
    __syncthreads();
    if (!lastFlag) return;
    __builtin_amdgcn_fence(__ATOMIC_ACQUIRE, "agent");   // no stale L2

    // exact reduce_topk_kernel body, 16 tokens per pass, 8 passes for TM=128
    const int rtx  = tid & 15;         // experts 4*rtx..4*rtx+3
    const int rty  = tid >> 4;         // token-in-group 0..15
    const int eB   = rtx << 2;
    const float4 bv = *(const float4*)&bias[eB];

    for (int grp = 0; grp < TM / 16; ++grp) {
        const int token = tokBase + grp * 16 + rty;

        float4 v = make_float4(0.f, 0.f, 0.f, 0.f);
        for (int s = 0; s < S; ++s) {
            const float4 p = *(const float4*)
                &partial[((size_t)s * tokens + token) * NEXP + eB];
            v.x += p.x; v.y += p.y; v.z += p.z; v.w += p.w;
        }
        float g[4] = { v.x + bv.x, v.y + bv.y, v.z + bv.z, v.w + bv.w };

        // local top-2 (ascending keeps lower index on ties, like lax.top_k)
        float v1 = g[0]; int i1 = eB;
        float v2 = -INFINITY; int i2 = -1;
        #pragma unroll
        for (int c = 1; c < 4; ++c) {
            const float vv = g[c];
            const int   ii = eB + c;
            if (vv > v1)      { v2 = v1; i2 = i1; v1 = vv; i1 = ii; }
            else if (vv > v2) { v2 = vv; i2 = ii; }
        }
        // 16-lane butterfly merge
        #pragma unroll
        for (int m = 1; m <= 8; m <<= 1) {
            const float ov1 = __shfl_xor(v1, m);
            const int   oi1 = __shfl_xor(i1, m);
            const float ov2 = __shfl_xor(v2, m);
            const int   oi2 = __shfl_xor(i2, m);
            const bool aw = (v1 > ov1) || (v1 == ov1 && i1 < oi1);
            const float nv1 = aw ? v1  : ov1;  const int ni1 = aw ? i1  : oi1;
            const float lv  = aw ? ov1 : v1;   const int li  = aw ? oi1 : i1;
            const float sv  = aw ? v2  : ov2;  const int si  = aw ? i2  : oi2;
            const bool sw = (sv > lv) || (sv == lv && si < li);
            v1 = nv1; i1 = ni1;
            v2 = sw ? sv : lv; i2 = sw ? si : li;
        }
        if (rtx == 0) {
            const float e2 = expf(v2 - v1);
            const float denom = 1.0f + e2;
            out[2 * token]     = (float)i1;
            out[2 * token + 1] = (float)i2;
            out[tokens * 2 + 2 * token]     = 1.0f / denom;
            out[tokens * 2 + 2 * token + 1] = e2 / denom;
        }
    }
}

extern "C" void kernel_launch(void* const* d_in, const int* in_sizes, int n_in,
                              void* d_out, int out_size, void* d_ws, size_t ws_size,
                              hipStream_t stream) {
    const float* inp  = (const float*)d_in[0];
    const float* W    = (const float*)d_in[1];
    const float* bias = (const float*)d_in[2];
    float* out = (float*)d_out;
    (void)n_in; (void)out_size;

    const int tokens = in_sizes[0] / KDIM;   // 16384
    const int nTiles = tokens / TM;          // 128

    // pick largest split S in {4,2,1}: partial buffer + counters must fit d_ws
    int S = 4;
    size_t ctrOff;
    for (;;) {
        const size_t pb = (size_t)S * tokens * NEXP * sizeof(float);
        ctrOff = (pb + 255) & ~(size_t)255;
        if (ctrOff + (size_t)nTiles * sizeof(int) <= ws_size || S == 1) break;
        S >>= 1;
    }
    float* partial = (float*)d_ws;
    int*   ctr     = (int*)((char*)d_ws + ctrOff);

    // counters are in poisoned workspace: zero them each call (capturable)
    hipMemsetAsync(ctr, 0, (size_t)nTiles * sizeof(int), stream);

    dim3 grid(nTiles, S);
    gate_fused_kernel<<<grid, 256, 0, stream>>>(
        inp, W, bias, partial, ctr, out, tokens, KDIM / S, S);
}

// Round 9
// 227.019 us; speedup vs baseline: 1.4453x; 1.4453x over previous
//
#include <hip/hip_runtime.h>
#include <math.h>

// MoE gate: gate = inp[16384,2048]f32 @ W[64,2048]^T + b[64]; top-2; softmax.
// d_out (float32): [tokens*2] indices-as-floats, then [tokens*2] scores.
//
// Round 11: exact round-0 kernel (best, 214.46us) with the 16-FMA inner body
// re-expressed as 8x v_pk_fma_f32 (VOP3P packed fp32: two independent IEEE
// fmas per instruction). Rationale: gate is VALU-ISSUE bound (~48us vs 42us
// practical v_fma floor per m07's 103 TF; all tiling/barrier/LDS/occupancy
// levers proven neutral in r6/r7; r8's fence-based fusion catastrophically
// regressed via L2 writeback storms and is reverted). Packing halves FMA
// instruction count; each half-lane chain keeps the identical kk-ascending
// fmaf order -> partials bitwise-identical to r0 -> absmax stays 0.0.

#define KDIM 2048
#define NEXP 64
#define TM 64
#define BK 32
#define LDSS 68   // 64 + 4 pad: 272 B row stride (mult of 16 -> b128-aligned)

typedef float v2f __attribute__((ext_vector_type(2)));

__global__ __launch_bounds__(256) void gate_partial_kernel(
    const float* __restrict__ inp,
    const float* __restrict__ W,
    float* __restrict__ partial,   // [S][tokens][NEXP]
    int tokens, int kPerSplit)
{
    __shared__ float As[BK][LDSS];   // As[k][token]
    __shared__ float Ws[BK][LDSS];   // Ws[k][expert]

    const int tid = threadIdx.x;
    const int tx  = tid & 15;        // experts 4*tx..4*tx+3
    const int ty  = tid >> 4;        // tokens 4*ty..4*ty+3
    const int tokBase = blockIdx.x * TM;
    const int split   = blockIdx.y;
    const int k0      = split * kPerSplit;

    // staging map: 64 rows x 32 cols f32 per tile, 2 passes of float4
    const int lrow = tid >> 3;          // 0..31
    const int lcol = (tid & 7) << 2;    // 0,4,...,28

    const float* aPtr0 = inp + (size_t)(tokBase + lrow)      * KDIM + k0 + lcol;
    const float* aPtr1 = inp + (size_t)(tokBase + lrow + 32) * KDIM + k0 + lcol;
    const float* wPtr0 = W   + (size_t)lrow        * KDIM + k0 + lcol;
    const float* wPtr1 = W   + (size_t)(lrow + 32) * KDIM + k0 + lcol;

    float4 aReg0 = *(const float4*)(aPtr0);
    float4 aReg1 = *(const float4*)(aPtr1);
    float4 wReg0 = *(const float4*)(wPtr0);
    float4 wReg1 = *(const float4*)(wPtr1);

    // acc2[r][0] = experts {4tx+0, 4tx+1}; acc2[r][1] = {4tx+2, 4tx+3}
    v2f acc2[4][2];
    #pragma unroll
    for (int r = 0; r < 4; ++r) {
        acc2[r][0] = (v2f)0.0f;
        acc2[r][1] = (v2f)0.0f;
    }

    const int NT = kPerSplit / BK;
    for (int kt = 0; kt < NT; ++kt) {
        __syncthreads();
        #pragma unroll
        for (int c = 0; c < 4; ++c) {
            As[lcol + c][lrow]      = ((const float*)&aReg0)[c];
            As[lcol + c][lrow + 32] = ((const float*)&aReg1)[c];
            Ws[lcol + c][lrow]      = ((const float*)&wReg0)[c];
            Ws[lcol + c][lrow + 32] = ((const float*)&wReg1)[c];
        }
        __syncthreads();
        if (kt + 1 < NT) {
            const int off = (kt + 1) * BK;
            aReg0 = *(const float4*)(aPtr0 + off);
            aReg1 = *(const float4*)(aPtr1 + off);
            wReg0 = *(const float4*)(wPtr0 + off);
            wReg1 = *(const float4*)(wPtr1 + off);
        }
        #pragma unroll 8
        for (int kk = 0; kk < BK; ++kk) {
            const float4 av = *(const float4*)&As[kk][ty << 2];
            const float4 wv = *(const float4*)&Ws[kk][tx << 2];
            v2f w01; w01.x = wv.x; w01.y = wv.y;
            v2f w23; w23.x = wv.z; w23.y = wv.w;
            const float a4[4] = {av.x, av.y, av.z, av.w};
            #pragma unroll
            for (int r = 0; r < 4; ++r) {
                v2f aa;
                aa.x = a4[r]; aa.y = a4[r];
                // two independent IEEE fmas per instr; per-half chain order
                // identical to the scalar fmaf version (kk ascending)
                asm("v_pk_fma_f32 %0, %1, %2, %0"
                    : "+v"(acc2[r][0]) : "v"(aa), "v"(w01));
                asm("v_pk_fma_f32 %0, %1, %2, %0"
                    : "+v"(acc2[r][1]) : "v"(aa), "v"(w23));
            }
        }
    }

    // write partials: [split][token][expert], float4 over experts, coalesced in tx
    const int eBase = tx << 2;
    #pragma unroll
    for (int r = 0; r < 4; ++r) {
        const int token = tokBase + (ty << 2) + r;
        float4 v = make_float4(acc2[r][0].x, acc2[r][0].y,
                               acc2[r][1].x, acc2[r][1].y);
        *(float4*)&partial[((size_t)split * tokens + token) * NEXP + eBase] = v;
    }
}

__global__ __launch_bounds__(256) void reduce_topk_kernel(
    const float* __restrict__ partial,
    const float* __restrict__ bias,
    float* __restrict__ out,
    int tokens, int S)
{
    const int tid = threadIdx.x;
    const int tx  = tid & 15;          // experts 4*tx..4*tx+3
    const int ty  = tid >> 4;          // 16 tokens per block
    const int token = blockIdx.x * 16 + ty;
    const int eBase = tx << 2;

    float4 v = make_float4(0.f, 0.f, 0.f, 0.f);
    for (int s = 0; s < S; ++s) {
        const float4 p = *(const float4*)&partial[((size_t)s * tokens + token) * NEXP + eBase];
        v.x += p.x; v.y += p.y; v.z += p.z; v.w += p.w;
    }
    const float4 bv = *(const float4*)&bias[eBase];
    float g[4] = { v.x + bv.x, v.y + bv.y, v.z + bv.z, v.w + bv.w };

    // local top-2 (ascending scan keeps lower index on ties, matching lax.top_k)
    float v1 = g[0]; int i1 = eBase;
    float v2 = -INFINITY; int i2 = -1;
    #pragma unroll
    for (int c = 1; c < 4; ++c) {
        const float vv = g[c];
        const int   ii = eBase + c;
        if (vv > v1)      { v2 = v1; i2 = i1; v1 = vv; i1 = ii; }
        else if (vv > v2) { v2 = vv; i2 = ii; }
    }
    // 16-lane butterfly merge
    #pragma unroll
    for (int m = 1; m <= 8; m <<= 1) {
        const float ov1 = __shfl_xor(v1, m);
        const int   oi1 = __shfl_xor(i1, m);
        const float ov2 = __shfl_xor(v2, m);
        const int   oi2 = __shfl_xor(i2, m);
        const bool aw = (v1 > ov1) || (v1 == ov1 && i1 < oi1);
        const float nv1 = aw ? v1  : ov1;  const int ni1 = aw ? i1  : oi1;
        const float lv  = aw ? ov1 : v1;   const int li  = aw ? oi1 : i1;
        const float sv  = aw ? v2  : ov2;  const int si  = aw ? i2  : oi2;
        const bool sw = (sv > lv) || (sv == lv && si < li);
        v1 = nv1; i1 = ni1;
        v2 = sw ? sv : lv; i2 = sw ? si : li;
    }
    if (tx == 0) {
        const float e2 = expf(v2 - v1);
        const float denom = 1.0f + e2;
        out[2 * token]     = (float)i1;
        out[2 * token + 1] = (float)i2;
        out[tokens * 2 + 2 * token]     = 1.0f / denom;
        out[tokens * 2 + 2 * token + 1] = e2 / denom;
    }
}

extern "C" void kernel_launch(void* const* d_in, const int* in_sizes, int n_in,
                              void* d_out, int out_size, void* d_ws, size_t ws_size,
                              hipStream_t stream) {
    const float* inp  = (const float*)d_in[0];
    const float* W    = (const float*)d_in[1];
    const float* bias = (const float*)d_in[2];
    float* out = (float*)d_out;
    float* partial = (float*)d_ws;

    const int tokens = in_sizes[0] / KDIM;   // 16384

    // pick largest split S in {4,2,1} whose partial buffer fits d_ws
    int S = 4;
    while (S > 1 && (size_t)S * tokens * NEXP * sizeof(float) > ws_size) S >>= 1;
    const int kPerSplit = KDIM / S;

    dim3 grid(tokens / TM, S);
    gate_partial_kernel<<<grid, 256, 0, stream>>>(inp, W, partial, tokens, kPerSplit);
    reduce_topk_kernel<<<tokens / 16, 256, 0, stream>>>(partial, bias, out, tokens, S);
}

// Round 10
// 217.966 us; speedup vs baseline: 1.5053x; 1.0415x over previous
//
#include <hip/hip_runtime.h>
#include <math.h>

// MoE gate: gate = inp[16384,2048]f32 @ W[64,2048]^T + b[64]; top-2; softmax.
// d_out (float32): [tokens*2] indices-as-floats, then [tokens*2] scores.
//
// Round 12: exact round-0 kernel (best, 214.46us) with the 16-FMA inner body
// expressed as __builtin_elementwise_fma on float2 vectors -> llvm.fma.v2f32
// -> v_pk_fma_f32, COMPILER-scheduled (r9's inline-asm pk attempt regressed
// 48->88us: forced v_movs for broadcasts/pairing + "+v" serialization; its
// absmax 0.0 proved pk numerics are bitwise-identical though). Per-component
// chains keep the identical kk-ascending fma order -> partials bitwise-
// identical to r0. __has_builtin fallback = exact r0 scalar path.

#define KDIM 2048
#define NEXP 64
#define TM 64
#define BK 32
#define LDSS 68   // 64 + 4 pad: 272 B row stride (mult of 16 -> b128-aligned)

typedef float v2f __attribute__((ext_vector_type(2)));

__global__ __launch_bounds__(256) void gate_partial_kernel(
    const float* __restrict__ inp,
    const float* __restrict__ W,
    float* __restrict__ partial,   // [S][tokens][NEXP]
    int tokens, int kPerSplit)
{
    __shared__ float As[BK][LDSS];   // As[k][token]
    __shared__ float Ws[BK][LDSS];   // Ws[k][expert]

    const int tid = threadIdx.x;
    const int tx  = tid & 15;        // experts 4*tx..4*tx+3
    const int ty  = tid >> 4;        // tokens 4*ty..4*ty+3
    const int tokBase = blockIdx.x * TM;
    const int split   = blockIdx.y;
    const int k0      = split * kPerSplit;

    // staging map: 64 rows x 32 cols f32 per tile, 2 passes of float4
    const int lrow = tid >> 3;          // 0..31
    const int lcol = (tid & 7) << 2;    // 0,4,...,28

    const float* aPtr0 = inp + (size_t)(tokBase + lrow)      * KDIM + k0 + lcol;
    const float* aPtr1 = inp + (size_t)(tokBase + lrow + 32) * KDIM + k0 + lcol;
    const float* wPtr0 = W   + (size_t)lrow        * KDIM + k0 + lcol;
    const float* wPtr1 = W   + (size_t)(lrow + 32) * KDIM + k0 + lcol;

    float4 aReg0 = *(const float4*)(aPtr0);
    float4 aReg1 = *(const float4*)(aPtr1);
    float4 wReg0 = *(const float4*)(wPtr0);
    float4 wReg1 = *(const float4*)(wPtr1);

    // acc2[r][0] = experts {4tx+0, 4tx+1}; acc2[r][1] = {4tx+2, 4tx+3}
    v2f acc2[4][2];
    #pragma unroll
    for (int r = 0; r < 4; ++r) {
        acc2[r][0] = (v2f)0.0f;
        acc2[r][1] = (v2f)0.0f;
    }

    const int NT = kPerSplit / BK;
    for (int kt = 0; kt < NT; ++kt) {
        __syncthreads();
        #pragma unroll
        for (int c = 0; c < 4; ++c) {
            As[lcol + c][lrow]      = ((const float*)&aReg0)[c];
            As[lcol + c][lrow + 32] = ((const float*)&aReg1)[c];
            Ws[lcol + c][lrow]      = ((const float*)&wReg0)[c];
            Ws[lcol + c][lrow + 32] = ((const float*)&wReg1)[c];
        }
        __syncthreads();
        if (kt + 1 < NT) {
            const int off = (kt + 1) * BK;
            aReg0 = *(const float4*)(aPtr0 + off);
            aReg1 = *(const float4*)(aPtr1 + off);
            wReg0 = *(const float4*)(wPtr0 + off);
            wReg1 = *(const float4*)(wPtr1 + off);
        }
        #pragma unroll 8
        for (int kk = 0; kk < BK; ++kk) {
            const float4 av = *(const float4*)&As[kk][ty << 2];
            const float4 wv = *(const float4*)&Ws[kk][tx << 2];
            const float a4[4] = {av.x, av.y, av.z, av.w};
            v2f w01; w01.x = wv.x; w01.y = wv.y;
            v2f w23; w23.x = wv.z; w23.y = wv.w;
            #pragma unroll
            for (int r = 0; r < 4; ++r) {
#if __has_builtin(__builtin_elementwise_fma)
                v2f aa; aa.x = a4[r]; aa.y = a4[r];
                // llvm.fma.v2f32 -> v_pk_fma_f32; per-component chain order
                // identical to scalar fmaf version (kk ascending)
                acc2[r][0] = __builtin_elementwise_fma(aa, w01, acc2[r][0]);
                acc2[r][1] = __builtin_elementwise_fma(aa, w23, acc2[r][1]);
#else
                acc2[r][0].x = fmaf(a4[r], w01.x, acc2[r][0].x);
                acc2[r][0].y = fmaf(a4[r], w01.y, acc2[r][0].y);
                acc2[r][1].x = fmaf(a4[r], w23.x, acc2[r][1].x);
                acc2[r][1].y = fmaf(a4[r], w23.y, acc2[r][1].y);
#endif
            }
        }
    }

    // write partials: [split][token][expert], float4 over experts, coalesced in tx
    const int eBase = tx << 2;
    #pragma unroll
    for (int r = 0; r < 4; ++r) {
        const int token = tokBase + (ty << 2) + r;
        float4 v = make_float4(acc2[r][0].x, acc2[r][0].y,
                               acc2[r][1].x, acc2[r][1].y);
        *(float4*)&partial[((size_t)split * tokens + token) * NEXP + eBase] = v;
    }
}

__global__ __launch_bounds__(256) void reduce_topk_kernel(
    const float* __restrict__ partial,
    const float* __restrict__ bias,
    float* __restrict__ out,
    int tokens, int S)
{
    const int tid = threadIdx.x;
    const int tx  = tid & 15;          // experts 4*tx..4*tx+3
    const int ty  = tid >> 4;          // 16 tokens per block
    const int token = blockIdx.x * 16 + ty;
    const int eBase = tx << 2;

    float4 v = make_float4(0.f, 0.f, 0.f, 0.f);
    for (int s = 0; s < S; ++s) {
        const float4 p = *(const float4*)&partial[((size_t)s * tokens + token) * NEXP + eBase];
        v.x += p.x; v.y += p.y; v.z += p.z; v.w += p.w;
    }
    const float4 bv = *(const float4*)&bias[eBase];
    float g[4] = { v.x + bv.x, v.y + bv.y, v.z + bv.z, v.w + bv.w };

    // local top-2 (ascending scan keeps lower index on ties, matching lax.top_k)
    float v1 = g[0]; int i1 = eBase;
    float v2 = -INFINITY; int i2 = -1;
    #pragma unroll
    for (int c = 1; c < 4; ++c) {
        const float vv = g[c];
        const int   ii = eBase + c;
        if (vv > v1)      { v2 = v1; i2 = i1; v1 = vv; i1 = ii; }
        else if (vv > v2) { v2 = vv; i2 = ii; }
    }
    // 16-lane butterfly merge
    #pragma unroll
    for (int m = 1; m <= 8; m <<= 1) {
        const float ov1 = __shfl_xor(v1, m);
        const int   oi1 = __shfl_xor(i1, m);
        const float ov2 = __shfl_xor(v2, m);
        const int   oi2 = __shfl_xor(i2, m);
        const bool aw = (v1 > ov1) || (v1 == ov1 && i1 < oi1);
        const float nv1 = aw ? v1  : ov1;  const int ni1 = aw ? i1  : oi1;
        const float lv  = aw ? ov1 : v1;   const int li  = aw ? oi1 : i1;
        const float sv  = aw ? v2  : ov2;  const int si  = aw ? i2  : oi2;
        const bool sw = (sv > lv) || (sv == lv && si < li);
        v1 = nv1; i1 = ni1;
        v2 = sw ? sv : lv; i2 = sw ? si : li;
    }
    if (tx == 0) {
        const float e2 = expf(v2 - v1);
        const float denom = 1.0f + e2;
        out[2 * token]     = (float)i1;
        out[2 * token + 1] = (float)i2;
        out[tokens * 2 + 2 * token]     = 1.0f / denom;
        out[tokens * 2 + 2 * token + 1] = e2 / denom;
    }
}

extern "C" void kernel_launch(void* const* d_in, const int* in_sizes, int n_in,
                              void* d_out, int out_size, void* d_ws, size_t ws_size,
                              hipStream_t stream) {
    const float* inp  = (const float*)d_in[0];
    const float* W    = (const float*)d_in[1];
    const float* bias = (const float*)d_in[2];
    float* out = (float*)d_out;
    float* partial = (float*)d_ws;

    const int tokens = in_sizes[0] / KDIM;   // 16384

    // pick largest split S in {4,2,1} whose partial buffer fits d_ws
    int S = 4;
    while (S > 1 && (size_t)S * tokens * NEXP * sizeof(float) > ws_size) S >>= 1;
    const int kPerSplit = KDIM / S;

    dim3 grid(tokens / TM, S);
    gate_partial_kernel<<<grid, 256, 0, stream>>>(inp, W, partial, tokens, kPerSplit);
    reduce_topk_kernel<<<tokens / 16, 256, 0, stream>>>(partial, bias, out, tokens, S);
}